// Round 1
// 253.198 us; speedup vs baseline: 1.0231x; 1.0231x over previous
//
#include <hip/hip_runtime.h>
#include <hip/hip_bf16.h>

// Flash-style block attention, MI355X gfx950. Round 5.
// R5 changes vs R4 (125us/dispatch, MfmaUtil 26%, VALUBusy 36%, ~40% idle):
//  - Double-buffered K/V LDS (2 x 37888 B). Residency was already 2 WGs/CU
//    (regs: 60 VGPR + AGPR accumulators > 64 total), so 75.8 KB/WG is free.
//  - Software-pipelined staging (T14): global loads for chunk c+1 issue
//    BEFORE chunk c's compute; fp32->bf16 hi/lo convert + ds_write happen
//    AFTER compute. ~700cy load latency hides under ~600cy MFMA+softmax.
//  - ONE __syncthreads per chunk (was 2): with double buffering, writes go
//    to buf[(c+1)&1] while reads come from buf[c&1] -> single barrier safe.
//  - Mask loads vectorized (4x dwordx4) and issued BEFORE the stage
//    prefetch: vmcnt is in-order, so waiting on masks mid-compute must not
//    force the stage loads (issued earlier) to drain.
// Predicted: dur 125 -> ~95us/dispatch, MfmaUtil -> ~33%, VALUBusy -> ~46%.

typedef __attribute__((ext_vector_type(8))) short bf16x8;
typedef __attribute__((ext_vector_type(4))) short bf16x4;
typedef __attribute__((ext_vector_type(4))) float f32x4;

#define MFMA32(A, B, C) __builtin_amdgcn_mfma_f32_16x16x32_bf16((A), (B), (C), 0, 0, 0)
#define MFMA16(A, B, C) __builtin_amdgcn_mfma_f32_16x16x16bf16_1k((A), (B), (C), 0, 0, 0)

__device__ __forceinline__ unsigned int cvt_pk(float a, float b) {
    __hip_bfloat162 h = __float22bfloat162_rn(float2{a, b});
    union { __hip_bfloat162 h; unsigned int u; } c;
    c.h = h;
    return c.u;
}
__device__ __forceinline__ void split2(float a, float b, unsigned int& hi, unsigned int& lo) {
    unsigned int h = cvt_pk(a, b);
    float ra = a - __uint_as_float(h << 16);
    float rb = b - __uint_as_float(h & 0xFFFF0000u);
    hi = h;
    lo = cvt_pk(ra, rb);
}
__device__ __forceinline__ void split8v(f32x4 a, f32x4 b, bf16x8& hi, bf16x8& lo) {
    union { bf16x8 v; unsigned int w[4]; } H, L;
    split2(a[0], a[1], H.w[0], L.w[0]);
    split2(a[2], a[3], H.w[1], L.w[1]);
    split2(b[0], b[1], H.w[2], L.w[2]);
    split2(b[2], b[3], H.w[3], L.w[3]);
    hi = H.v; lo = L.v;
}
__device__ __forceinline__ void split4v(f32x4 s, bf16x4& hi, bf16x4& lo) {
    union { bf16x4 v; unsigned int w[2]; } H, L;
    split2(s[0], s[1], H.w[0], L.w[0]);
    split2(s[2], s[3], H.w[1], L.w[1]);
    hi = H.v; lo = L.v;
}

// Per-buffer layout: K_hi [64][72] (9216 B) | K_lo (9216 B) |
//                    V^T_hi [64][76] (9728 B) | V^T_lo (9728 B) = 37888 B.
// Two buffers = 75776 B; epilogue reuses bytes [0,34816) as [128][68] f32.
#define BUF_BYTES 37888

__global__ __launch_bounds__(512, 4) void block_attn_kernel(
    const float* __restrict__ q, const float* __restrict__ k,
    const float* __restrict__ v, const float* __restrict__ amask,
    const float* __restrict__ gk, const float* __restrict__ gv,
    const float* __restrict__ gmask, float* __restrict__ out) {
    constexpr int Hh = 16, Tt = 4096, Gg = 128;

    __shared__ __align__(16) unsigned char lds[2 * BUF_BYTES];
    float* o_scr = (float*)lds;  // [128][68] epilogue scratch

    const int blk = blockIdx.x;
    const int bh  = blockIdx.z * Hh + blockIdx.y;
    const int tid  = threadIdx.x;
    const int lane = tid & 63;
    const int wv   = tid >> 6;      // 0..7, wave owns q-rows [wv*16, wv*16+16)
    const int c15  = lane & 15;
    const int quad = lane >> 4;

    const float* qptr = q + ((size_t)bh * Tt + blk * 128) * 64;
    const float* kptr = k + ((size_t)bh * Tt + blk * 128) * 64;
    const float* vptr = v + ((size_t)bh * Tt + blk * 128) * 64;
    const float* gkp  = gk + (size_t)bh * Gg * 64;
    const float* gvp  = gv + (size_t)bh * Gg * 64;
    const float* amp  = amask + (size_t)bh * Tt + blk * 128;
    const float* gmp  = gmask + (size_t)bh * Gg;

    // ---- Q as B-operand frags: n=c15 (q-row), k=d=32*half+quad*8+j ----
    bf16x8 qbh[2], qbl[2];
    {
        int row = wv * 16 + c15;
#pragma unroll
        for (int h = 0; h < 2; ++h) {
            f32x4 a = *(const f32x4*)(qptr + row * 64 + h * 32 + quad * 8);
            f32x4 b = *(const f32x4*)(qptr + row * 64 + h * 32 + quad * 8 + 4);
            split8v(a, b, qbh[h], qbl[h]);
        }
    }

    // ---- staging geometry (waves 0-3: K chunk; waves 4-7: V^T chunk) ----
    const int slot = tid & 15;
    const int r0k  = (tid >> 4) & 15;
    const int tV   = tid & 255;            // tid-256 for waves 4-7
    const int key0 = 4 * (tV & 15);
    const int d0v  = 4 * ((tV >> 4) & 3) + 16 * (tV >> 6);

    int soff[4];
    const float *sloc, *sglb;
    if (wv < 4) {
        sloc = kptr; sglb = gkp;
#pragma unroll
        for (int i = 0; i < 4; ++i) soff[i] = (r0k + i * 16) * 64 + slot * 4;
    } else {
        sloc = vptr; sglb = gvp;
#pragma unroll
        for (int j = 0; j < 4; ++j) soff[j] = (key0 + j) * 64 + d0v;
    }

    f32x4 stg[4];
    auto stage_load = [&](int c) {
        const float* s = (c < 2) ? (sloc + c * 4096) : (sglb + (c - 2) * 4096);
#pragma unroll
        for (int j = 0; j < 4; ++j) stg[j] = *(const f32x4*)(s + soff[j]);
    };
    auto stage_store = [&](int b) {
        unsigned char* base = lds + b * BUF_BYTES;
        if (wv < 4) {
            unsigned short* kh = (unsigned short*)base;
            unsigned short* kl = (unsigned short*)(base + 9216);
#pragma unroll
            for (int i = 0; i < 4; ++i) {
                unsigned int h0, l0, h1, l1;
                split2(stg[i][0], stg[i][1], h0, l0);
                split2(stg[i][2], stg[i][3], h1, l1);
                int o = (r0k + i * 16) * 72 + slot * 4;
                *reinterpret_cast<uint2*>(kh + o) = make_uint2(h0, h1);
                *reinterpret_cast<uint2*>(kl + o) = make_uint2(l0, l1);
            }
        } else {
            unsigned short* vh = (unsigned short*)(base + 18432);
            unsigned short* vl = (unsigned short*)(base + 28160);
#pragma unroll
            for (int i = 0; i < 4; ++i) {
                unsigned int h0, l0, h1, l1;
                split2(stg[0][i], stg[1][i], h0, l0);
                split2(stg[2][i], stg[3][i], h1, l1);
                int o = (d0v + i) * 76 + key0;
                *reinterpret_cast<uint2*>(vh + o) = make_uint2(h0, h1);
                *reinterpret_cast<uint2*>(vl + o) = make_uint2(l0, l1);
            }
        }
    };

    // ---- prologue: fill buffer 0 with chunk 0 ----
    stage_load(0);
    stage_store(0);
    __syncthreads();

    const f32x4 zero4 = {0.f, 0.f, 0.f, 0.f};
    f32x4 ctx[4];  // ctx^T[d=dm*16+quad*4+r][q=c15]
#pragma unroll
    for (int dm = 0; dm < 4; ++dm) ctx[dm] = zero4;
    float m_run = -3.4e38f, l_run = 0.f;

#pragma unroll
    for (int c = 0; c < 4; ++c) {
        // masks for THIS chunk, vectorized; issued first so their vmcnt wait
        // mid-compute does not drain the stage prefetch issued after them.
        const float* mb = (c < 2) ? (amp + c * 64) : (gmp + (c - 2) * 64);
        f32x4 mk[4];
#pragma unroll
        for (int km = 0; km < 4; ++km) mk[km] = *(const f32x4*)(mb + km * 16 + quad * 4);

        // prefetch NEXT chunk's global data into registers (T14 issue-early)
        if (c < 3) stage_load(c + 1);

        unsigned char* rb = lds + (c & 1) * BUF_BYTES;
        const unsigned short* k_hi = (const unsigned short*)rb;
        const unsigned short* k_lo = (const unsigned short*)(rb + 9216);
        const unsigned short* v_hi = (const unsigned short*)(rb + 18432);
        const unsigned short* v_lo = (const unsigned short*)(rb + 28160);

        // ---- S^T = K·Q^T : D[m=key=km*16+quad*4+r][n=q=c15] ----
        f32x4 S[4];
#pragma unroll
        for (int km = 0; km < 4; ++km) S[km] = zero4;

#pragma unroll
        for (int km = 0; km < 4; ++km) {
            int krow = km * 16 + c15;
            bf16x8 kh0 = *(const bf16x8*)(k_hi + krow * 72 + quad * 8);
            bf16x8 kh1 = *(const bf16x8*)(k_hi + krow * 72 + quad * 8 + 32);
            bf16x8 kl0 = *(const bf16x8*)(k_lo + krow * 72 + quad * 8);
            bf16x8 kl1 = *(const bf16x8*)(k_lo + krow * 72 + quad * 8 + 32);
            f32x4 a = S[km];
            a = MFMA32(kh0, qbh[0], a);
            a = MFMA32(kh1, qbh[1], a);
            a = MFMA32(kh0, qbl[0], a);
            a = MFMA32(kh1, qbl[1], a);
            a = MFMA32(kl0, qbh[0], a);
            a = MFMA32(kl1, qbh[1], a);
            S[km] = a;
        }

        // ---- online softmax over keys (rows of S^T) + P^T frags ----
        bf16x4 ph[4], pl[4];
        {
            float mx = -3.4e38f;
#pragma unroll
            for (int km = 0; km < 4; ++km)
#pragma unroll
                for (int r = 0; r < 4; ++r) {
                    float s = fmaf(S[km][r], 0.125f, mk[km][r]);
                    S[km][r] = s;
                    mx = fmaxf(mx, s);
                }
            mx = fmaxf(mx, __shfl_xor(mx, 16));
            mx = fmaxf(mx, __shfl_xor(mx, 32));
            float mo = m_run;
            float mn = fmaxf(mo, mx);
            float alpha = __expf(mo - mn);
            m_run = mn;
            float sm = 0.f;
#pragma unroll
            for (int km = 0; km < 4; ++km)
#pragma unroll
                for (int r = 0; r < 4; ++r) {
                    float e = __expf(S[km][r] - mn);
                    S[km][r] = e;
                    sm += e;
                }
            sm += __shfl_xor(sm, 16);
            sm += __shfl_xor(sm, 32);
            l_run = l_run * alpha + sm;
#pragma unroll
            for (int km = 0; km < 4; ++km) split4v(S[km], ph[km], pl[km]);
#pragma unroll
            for (int dm = 0; dm < 4; ++dm) {
                ctx[dm][0] *= alpha; ctx[dm][1] *= alpha;
                ctx[dm][2] *= alpha; ctx[dm][3] *= alpha;
            }
        }

        // ---- ctx^T += V^T · P^T (mfma 16x16x16, A[m=d][k=key=quad*4+r]) ----
#pragma unroll
        for (int dm = 0; dm < 4; ++dm) {
            int drow = dm * 16 + c15;
            f32x4 a = ctx[dm];
#pragma unroll
            for (int km = 0; km < 4; ++km) {
                bf16x4 vh = *(const bf16x4*)(v_hi + drow * 76 + km * 16 + quad * 4);
                bf16x4 vl = *(const bf16x4*)(v_lo + drow * 76 + km * 16 + quad * 4);
                a = MFMA16(vh, ph[km], a);
                a = MFMA16(vh, pl[km], a);
                a = MFMA16(vl, ph[km], a);
            }
            ctx[dm] = a;
        }

        // convert+write NEXT chunk into the other buffer (T14 write-late);
        // vmcnt wait on the prefetch lands here, after compute.
        if (c < 3) stage_store((c + 1) & 1);
        __syncthreads();
    }

    // ---- epilogue: normalize, bounce ctx^T through LDS, coalesced store ----
    // (loop-end barrier already separates last chunk's LDS reads from reuse)
    {
        float inv = 1.0f / l_run;
        int row = wv * 16 + c15;
#pragma unroll
        for (int dm = 0; dm < 4; ++dm) {
            f32x4 o = ctx[dm];
            o[0] *= inv; o[1] *= inv; o[2] *= inv; o[3] *= inv;
            *(f32x4*)(o_scr + row * 68 + dm * 16 + quad * 4) = o;
        }
    }
    __syncthreads();
    {
        float* op = out + ((size_t)bh * Tt + blk * 128) * 64;
        const int oslot = tid & 15, or0 = tid >> 4;  // or0 0..31
#pragma unroll
        for (int i = 0; i < 4; ++i) {
            int row = or0 + i * 32;
            f32x4 val = *(const f32x4*)(o_scr + row * 68 + oslot * 4);
            *(f32x4*)(op + row * 64 + oslot * 4) = val;
        }
    }
}

extern "C" void kernel_launch(void* const* d_in, const int* in_sizes, int n_in,
                              void* d_out, int out_size, void* d_ws, size_t ws_size,
                              hipStream_t stream) {
    (void)in_sizes; (void)n_in; (void)d_ws; (void)ws_size; (void)out_size;
    const float* q  = (const float*)d_in[0];
    const float* k  = (const float*)d_in[1];
    const float* v  = (const float*)d_in[2];
    const float* am = (const float*)d_in[3];
    const float* gk = (const float*)d_in[4];
    const float* gv = (const float*)d_in[5];
    const float* gm = (const float*)d_in[6];
    dim3 grid(32, 16, 4);
    block_attn_kernel<<<grid, dim3(512), 0, stream>>>(q, k, v, am, gk, gv, gm, (float*)d_out);
}

// Round 2
// 238.286 us; speedup vs baseline: 1.0872x; 1.0626x over previous
//
#include <hip/hip_runtime.h>
#include <hip/hip_bf16.h>

// Flash-style block attention, MI355X gfx950. Round 6.
// R6 vs R5 (122us/dispatch, MfmaUtil 26%, VALUBusy 36%): cut the serial
// per-chunk critical path (QK^T -> softmax -> PV) instead of memory.
//  - P single-bf16 (drop pl): PV = (vh+vl)*ph, 48->32 MFMA16, split4v -> 8 cvt_pk.
//  - exp2 domain: scale/mask pre-multiplied by log2(e); bare v_exp_f32.
//  - T13 defer-max, THR=8 (log2 units): cross-lane max + alpha rescale only
//    when the wave-uniform __all vote fails (chunk 0 only for N(0,1) data).
//  - l-sum deferred: per-lane partials (16 keys each), cross-quad reduce once
//    in epilogue. Steady-state softmax has ZERO cross-lane shuffles.
//  - V hi/lo interleaved in LDS -> PV reads 16x ds_read_b128 (was 32x b64).
//  - T5 s_setprio(1) around MFMA clusters.
// Predicted: dur -> ~95us/dispatch, VALUBusy -> ~26%, absmax ~0.005.

typedef __attribute__((ext_vector_type(8))) short bf16x8;
typedef __attribute__((ext_vector_type(4))) short bf16x4;
typedef __attribute__((ext_vector_type(4))) float f32x4;

#define MFMA32(A, B, C) __builtin_amdgcn_mfma_f32_16x16x32_bf16((A), (B), (C), 0, 0, 0)
#define MFMA16(A, B, C) __builtin_amdgcn_mfma_f32_16x16x16bf16_1k((A), (B), (C), 0, 0, 0)

__device__ __forceinline__ unsigned int cvt_pk(float a, float b) {
    __hip_bfloat162 h = __float22bfloat162_rn(float2{a, b});
    union { __hip_bfloat162 h; unsigned int u; } c;
    c.h = h;
    return c.u;
}
__device__ __forceinline__ void split2(float a, float b, unsigned int& hi, unsigned int& lo) {
    unsigned int h = cvt_pk(a, b);
    float ra = a - __uint_as_float(h << 16);
    float rb = b - __uint_as_float(h & 0xFFFF0000u);
    hi = h;
    lo = cvt_pk(ra, rb);
}
__device__ __forceinline__ void split8v(f32x4 a, f32x4 b, bf16x8& hi, bf16x8& lo) {
    union { bf16x8 v; unsigned int w[4]; } H, L;
    split2(a[0], a[1], H.w[0], L.w[0]);
    split2(a[2], a[3], H.w[1], L.w[1]);
    split2(b[0], b[1], H.w[2], L.w[2]);
    split2(b[2], b[3], H.w[3], L.w[3]);
    hi = H.v; lo = L.v;
}

// Per-buffer layout: K_hi [64][72] (9216 B) | K_lo [64][72] (9216 B) |
// V^T interleaved [64][152 halfwords] (19456 B): per d-row, per 4-key group:
// [hi x4 (8B) | lo x4 (8B)]. Total 37888 B per buffer, two buffers = 75776 B.
// Epilogue reuses bytes [0,34816) as [128][68] f32.
#define BUF_BYTES 37888

#define LOG2E 1.44269504f
#define QSCALE 0.180336880f  /* 0.125 * log2(e) */
#define DEFER_THR 8.0f       /* P bounded by 2^8 when max update deferred */

__global__ __launch_bounds__(512, 4) void block_attn_kernel(
    const float* __restrict__ q, const float* __restrict__ k,
    const float* __restrict__ v, const float* __restrict__ amask,
    const float* __restrict__ gk, const float* __restrict__ gv,
    const float* __restrict__ gmask, float* __restrict__ out) {
    constexpr int Hh = 16, Tt = 4096, Gg = 128;

    __shared__ __align__(16) unsigned char lds[2 * BUF_BYTES];
    float* o_scr = (float*)lds;  // [128][68] epilogue scratch

    const int blk = blockIdx.x;
    const int bh  = blockIdx.z * Hh + blockIdx.y;
    const int tid  = threadIdx.x;
    const int lane = tid & 63;
    const int wv   = tid >> 6;      // 0..7, wave owns q-rows [wv*16, wv*16+16)
    const int c15  = lane & 15;
    const int quad = lane >> 4;

    const float* qptr = q + ((size_t)bh * Tt + blk * 128) * 64;
    const float* kptr = k + ((size_t)bh * Tt + blk * 128) * 64;
    const float* vptr = v + ((size_t)bh * Tt + blk * 128) * 64;
    const float* gkp  = gk + (size_t)bh * Gg * 64;
    const float* gvp  = gv + (size_t)bh * Gg * 64;
    const float* amp  = amask + (size_t)bh * Tt + blk * 128;
    const float* gmp  = gmask + (size_t)bh * Gg;

    // ---- Q as B-operand frags: n=c15 (q-row), k=d=32*half+quad*8+j ----
    bf16x8 qbh[2], qbl[2];
    {
        int row = wv * 16 + c15;
#pragma unroll
        for (int h = 0; h < 2; ++h) {
            f32x4 a = *(const f32x4*)(qptr + row * 64 + h * 32 + quad * 8);
            f32x4 b = *(const f32x4*)(qptr + row * 64 + h * 32 + quad * 8 + 4);
            split8v(a, b, qbh[h], qbl[h]);
        }
    }

    // ---- staging geometry (waves 0-3: K chunk; waves 4-7: V^T chunk) ----
    const int slot = tid & 15;
    const int r0k  = (tid >> 4) & 15;
    const int tV   = tid & 255;            // tid-256 for waves 4-7
    const int key0 = 4 * (tV & 15);
    const int d0v  = 4 * ((tV >> 4) & 3) + 16 * (tV >> 6);

    int soff[4];
    const float *sloc, *sglb;
    if (wv < 4) {
        sloc = kptr; sglb = gkp;
#pragma unroll
        for (int i = 0; i < 4; ++i) soff[i] = (r0k + i * 16) * 64 + slot * 4;
    } else {
        sloc = vptr; sglb = gvp;
#pragma unroll
        for (int j = 0; j < 4; ++j) soff[j] = (key0 + j) * 64 + d0v;
    }

    f32x4 stg[4];
    auto stage_load = [&](int c) {
        const float* s = (c < 2) ? (sloc + c * 4096) : (sglb + (c - 2) * 4096);
#pragma unroll
        for (int j = 0; j < 4; ++j) stg[j] = *(const f32x4*)(s + soff[j]);
    };
    auto stage_store = [&](int b) {
        unsigned char* base = lds + b * BUF_BYTES;
        if (wv < 4) {
            unsigned short* kh = (unsigned short*)base;
            unsigned short* kl = (unsigned short*)(base + 9216);
#pragma unroll
            for (int i = 0; i < 4; ++i) {
                unsigned int h0, l0, h1, l1;
                split2(stg[i][0], stg[i][1], h0, l0);
                split2(stg[i][2], stg[i][3], h1, l1);
                int o = (r0k + i * 16) * 72 + slot * 4;
                *reinterpret_cast<uint2*>(kh + o) = make_uint2(h0, h1);
                *reinterpret_cast<uint2*>(kl + o) = make_uint2(l0, l1);
            }
        } else {
            unsigned short* vb = (unsigned short*)(base + 18432);
#pragma unroll
            for (int i = 0; i < 4; ++i) {
                unsigned int h0, l0, h1, l1;
                split2(stg[0][i], stg[1][i], h0, l0);
                split2(stg[2][i], stg[3][i], h1, l1);
                // interleaved: per d-row, per 4-key group: [hi x4 | lo x4]
                int o = (d0v + i) * 152 + key0 * 2;  // halfword index, 16B-aligned
                *reinterpret_cast<uint4*>(vb + o) = make_uint4(h0, h1, l0, l1);
            }
        }
    };

    // ---- prologue: fill buffer 0 with chunk 0 ----
    stage_load(0);
    stage_store(0);
    __syncthreads();

    const f32x4 zero4 = {0.f, 0.f, 0.f, 0.f};
    f32x4 ctx[4];  // ctx^T[d=dm*16+quad*4+r][q=c15]
#pragma unroll
    for (int dm = 0; dm < 4; ++dm) ctx[dm] = zero4;
    float m_run = -3.4e38f;  // running max, log2 units
    float l_run = 0.f;       // PER-LANE partial (this lane's 16 keys); reduced in epilogue

#pragma unroll
    for (int c = 0; c < 4; ++c) {
        // masks for THIS chunk, vectorized; issued before the stage prefetch
        // so their vmcnt wait cannot drain the prefetch behind them.
        const float* mb = (c < 2) ? (amp + c * 64) : (gmp + (c - 2) * 64);
        f32x4 mkl[4];
#pragma unroll
        for (int km = 0; km < 4; ++km) {
            f32x4 m = *(const f32x4*)(mb + km * 16 + quad * 4);
            mkl[km] = m * LOG2E;  // log2 domain
        }

        // prefetch NEXT chunk's global data into registers (T14 issue-early)
        if (c < 3) stage_load(c + 1);

        unsigned char* rb = lds + (c & 1) * BUF_BYTES;
        const unsigned short* k_hi = (const unsigned short*)rb;
        const unsigned short* k_lo = (const unsigned short*)(rb + 9216);
        const unsigned int*   v_il = (const unsigned int*)(rb + 18432);  // [64][76] u32

        // ---- S^T = K·Q^T : D[m=key=km*16+quad*4+r][n=q=c15] ----
        f32x4 S[4];
#pragma unroll
        for (int km = 0; km < 4; ++km) S[km] = zero4;

        __builtin_amdgcn_s_setprio(1);
#pragma unroll
        for (int km = 0; km < 4; ++km) {
            int krow = km * 16 + c15;
            bf16x8 kh0 = *(const bf16x8*)(k_hi + krow * 72 + quad * 8);
            bf16x8 kh1 = *(const bf16x8*)(k_hi + krow * 72 + quad * 8 + 32);
            bf16x8 kl0 = *(const bf16x8*)(k_lo + krow * 72 + quad * 8);
            bf16x8 kl1 = *(const bf16x8*)(k_lo + krow * 72 + quad * 8 + 32);
            f32x4 a = S[km];
            a = MFMA32(kh0, qbh[0], a);
            a = MFMA32(kh1, qbh[1], a);
            a = MFMA32(kh0, qbl[0], a);
            a = MFMA32(kh1, qbl[1], a);
            a = MFMA32(kl0, qbh[0], a);
            a = MFMA32(kl1, qbh[1], a);
            S[km] = a;
        }
        __builtin_amdgcn_s_setprio(0);

        // ---- online softmax, log2 domain, deferred max + deferred sum ----
        bf16x4 ph[4];
        {
            // s' = S*0.125*log2e + mask*log2e; per-lane max over this lane's 16 keys
            float pmax = -3.4e38f;
#pragma unroll
            for (int km = 0; km < 4; ++km)
#pragma unroll
                for (int r = 0; r < 4; ++r) {
                    float s = fmaf(S[km][r], QSCALE, mkl[km][r]);
                    S[km][r] = s;
                    pmax = fmaxf(pmax, s);
                }
            // T13: only do the cross-lane reduce + rescale when some row's max
            // grew past the threshold (wave-uniform vote; chunk 0 always fails).
            if (!__all(pmax <= m_run + DEFER_THR)) {
                float mx = fmaxf(pmax, __shfl_xor(pmax, 16));
                mx = fmaxf(mx, __shfl_xor(mx, 32));
                float mn = fmaxf(m_run, mx);
                float alpha = __builtin_amdgcn_exp2f(m_run - mn);
                m_run = mn;
                l_run *= alpha;
#pragma unroll
                for (int dm = 0; dm < 4; ++dm) {
                    ctx[dm][0] *= alpha; ctx[dm][1] *= alpha;
                    ctx[dm][2] *= alpha; ctx[dm][3] *= alpha;
                }
            }
            float sm = 0.f;
#pragma unroll
            for (int km = 0; km < 4; ++km) {
#pragma unroll
                for (int r = 0; r < 4; ++r) {
                    float e = __builtin_amdgcn_exp2f(S[km][r] - m_run);
                    S[km][r] = e;
                    sm += e;
                }
                union { bf16x4 b; uint2 u; } P;
                P.u.x = cvt_pk(S[km][0], S[km][1]);
                P.u.y = cvt_pk(S[km][2], S[km][3]);
                ph[km] = P.b;
            }
            l_run += sm;  // per-lane partial; cross-quad reduce in epilogue
        }

        // ---- ctx^T += (V^T_hi + V^T_lo) · P^T (mfma 16x16x16) ----
        __builtin_amdgcn_s_setprio(1);
#pragma unroll
        for (int dm = 0; dm < 4; ++dm) {
            int drow = dm * 16 + c15;
            f32x4 a = ctx[dm];
#pragma unroll
            for (int km = 0; km < 4; ++km) {
                uint4 w = *(const uint4*)(v_il + drow * 76 + (km * 4 + quad) * 4);
                union { uint2 u; bf16x4 b; } vh, vl;
                vh.u = make_uint2(w.x, w.y);
                vl.u = make_uint2(w.z, w.w);
                a = MFMA16(vh.b, ph[km], a);
                a = MFMA16(vl.b, ph[km], a);
            }
            ctx[dm] = a;
        }
        __builtin_amdgcn_s_setprio(0);

        // convert+write NEXT chunk into the other buffer (T14 write-late)
        if (c < 3) stage_store((c + 1) & 1);
        __syncthreads();
    }

    // ---- epilogue: reduce l across quads, normalize, bounce through LDS ----
    {
        float l = l_run;
        l += __shfl_xor(l, 16);
        l += __shfl_xor(l, 32);
        float inv = 1.0f / l;
        int row = wv * 16 + c15;
#pragma unroll
        for (int dm = 0; dm < 4; ++dm) {
            f32x4 o = ctx[dm];
            o[0] *= inv; o[1] *= inv; o[2] *= inv; o[3] *= inv;
            *(f32x4*)(o_scr + row * 68 + dm * 16 + quad * 4) = o;
        }
    }
    __syncthreads();
    {
        float* op = out + ((size_t)bh * Tt + blk * 128) * 64;
        const int oslot = tid & 15, or0 = tid >> 4;  // or0 0..31
#pragma unroll
        for (int i = 0; i < 4; ++i) {
            int row = or0 + i * 32;
            f32x4 val = *(const f32x4*)(o_scr + row * 68 + oslot * 4);
            *(f32x4*)(op + row * 64 + oslot * 4) = val;
        }
    }
}

extern "C" void kernel_launch(void* const* d_in, const int* in_sizes, int n_in,
                              void* d_out, int out_size, void* d_ws, size_t ws_size,
                              hipStream_t stream) {
    (void)in_sizes; (void)n_in; (void)d_ws; (void)ws_size; (void)out_size;
    const float* q  = (const float*)d_in[0];
    const float* k  = (const float*)d_in[1];
    const float* v  = (const float*)d_in[2];
    const float* am = (const float*)d_in[3];
    const float* gk = (const float*)d_in[4];
    const float* gv = (const float*)d_in[5];
    const float* gm = (const float*)d_in[6];
    dim3 grid(32, 16, 4);
    block_attn_kernel<<<grid, dim3(512), 0, stream>>>(q, k, v, am, gk, gv, gm, (float*)d_out);
}